// Round 1
// baseline (493.935 us; speedup 1.0000x reference)
//
#include <hip/hip_runtime.h>

typedef __bf16 bf16_t;
typedef __bf16 bf16x8 __attribute__((ext_vector_type(8)));
typedef float  f32x4  __attribute__((ext_vector_type(4)));

#define NPIX 2048
#define NS   64
#define NK   8
#define NSAMP (NPIX*NS)          // 131072
#define NROWS (NSAMP*NK)         // 1048576
#define TROWS 64
#define NTILES (NROWS/TROWS)     // 16384
#define XSTR 104                 // 96 cols + 8 pad (bf16)
#define HSTR 136                 // 128 cols + 8 pad (bf16)

// packed-weight fragment bases (in bf16x8 units)
#define PK_W0 0
#define PK_W1 1536               // W0p: 8 ntiles * 3 ksteps * 64
#define PK_W2 3584               // W1p: 8*4*64 = 2048
#define PK_WA 5632               // W2p: 2048
#define PK_WR 6656               // Wa0p: 4*4*64 = 1024
#define PK_TOT 7680              // Wr0p: 1024 -> total 61440 bf16 = 122880 B

#define WS_AR_BYTES 122880       // float4 per sample after packed weights

// ---------------------------------------------------------------------------
// Pack W (row-major [KD,ND] fp32) into MFMA B-fragment order, bf16:
// elem index e = ((t*KS + s)*64 + l)*8 + j  holds  W[s*32 + (l>>4)*8 + j][t*16 + (l&15)]
// ---------------------------------------------------------------------------
__global__ void pack_weights(const float* __restrict__ W0, const float* __restrict__ W1,
                             const float* __restrict__ W2, const float* __restrict__ Wa0,
                             const float* __restrict__ Wr0, bf16_t* __restrict__ dst0) {
  int tid = blockIdx.x * blockDim.x + threadIdx.x;
  if (tid >= PK_TOT * 8) return;
  const float* src; bf16_t* dst; int e, KD, ND, KS;
  if (tid < 12288)      { src = W0;  dst = dst0;         e = tid;         KD = 88;  ND = 128; KS = 3; }
  else if (tid < 28672) { src = W1;  dst = dst0 + 12288; e = tid - 12288; KD = 128; ND = 128; KS = 4; }
  else if (tid < 45056) { src = W2;  dst = dst0 + 28672; e = tid - 28672; KD = 128; ND = 128; KS = 4; }
  else if (tid < 53248) { src = Wa0; dst = dst0 + 45056; e = tid - 45056; KD = 128; ND = 64;  KS = 4; }
  else                  { src = Wr0; dst = dst0 + 53248; e = tid - 53248; KD = 128; ND = 64;  KS = 4; }
  int j = e & 7, l = (e >> 3) & 63, f = e >> 9;
  int s = f % KS, t = f / KS;
  int row = s * 32 + (l >> 4) * 8 + j;
  int col = t * 16 + (l & 15);
  float v = (row < KD) ? src[row * ND + col] : 0.f;
  dst[e] = (bf16_t)v;
}

// ---------------------------------------------------------------------------
// Main fused kernel: gather+posenc -> 3-layer MLP (bf16 MFMA) -> K-reduce ->
// heads (MFMA) -> sigmoid -> (r,g,b,alpha) per sample.
// Block: 512 thr (8 waves). Wave = (colpair cp = wid&3, rowhalf rh = wid>>2).
// Each wave: 2 n-tiles x 2 row-groups of 16 => B frags live in registers.
// ---------------------------------------------------------------------------
__global__ __launch_bounds__(512)
void nerf_main(const float* __restrict__ map_xyz, const float* __restrict__ map_feat,
               const int* __restrict__ ind, const float* __restrict__ sample_xyz,
               const float* __restrict__ b0g, const float* __restrict__ b1g,
               const float* __restrict__ b2g, const float* __restrict__ ba0g,
               const float* __restrict__ wa1g, const float* __restrict__ ba1g,
               const float* __restrict__ br0g, const float* __restrict__ wr1g,
               const float* __restrict__ br1g, const bf16_t* __restrict__ wpack,
               float* __restrict__ ar_out)
{
  __shared__ __align__(16) bf16_t sX[TROWS * XSTR];     // 13312 B
  __shared__ __align__(16) bf16_t sHa[TROWS * HSTR];    // 17408 B
  __shared__ __align__(16) bf16_t sHb[TROWS * HSTR];    // 17408 B
  __shared__ __align__(16) bf16_t sFS[16 * HSTR];       // 4352 B (rows 8..15 stay zero)
  __shared__ float sWt[TROWS];
  __shared__ float sWs[8];
  __shared__ float sA[8 * 68];
  __shared__ float sR[8 * 68];
  __shared__ float sWa1[64];
  __shared__ float sWr1[192];

  const int tid = threadIdx.x;
  const int wid = tid >> 6, l = tid & 63;
  const int q = l >> 4, n = l & 15;
  const int cp = wid & 3, rh = wid >> 2;

  // ---- persistent register B-fragments ----
  const bf16x8* pk = (const bf16x8*)wpack;
  bf16x8 w0f[2][3], w1f[2][4], w2f[2][4], hdf[4];
#pragma unroll
  for (int nt = 0; nt < 2; nt++) {
    int t = cp * 2 + nt;
#pragma unroll
    for (int s = 0; s < 3; s++) w0f[nt][s] = pk[PK_W0 + (t * 3 + s) * 64 + l];
#pragma unroll
    for (int s = 0; s < 4; s++) w1f[nt][s] = pk[PK_W1 + (t * 4 + s) * 64 + l];
#pragma unroll
    for (int s = 0; s < 4; s++) w2f[nt][s] = pk[PK_W2 + (t * 4 + s) * 64 + l];
  }
#pragma unroll
  for (int s = 0; s < 4; s++)
    hdf[s] = pk[(wid < 4 ? PK_WA : PK_WR) + (cp * 4 + s) * 64 + l];

  float bias0[2], bias1[2], bias2[2];
#pragma unroll
  for (int nt = 0; nt < 2; nt++) {
    int c = (cp * 2 + nt) * 16 + n;
    bias0[nt] = b0g[c]; bias1[nt] = b1g[c]; bias2[nt] = b2g[c];
  }
  const float biasH = (wid < 4) ? ba0g[cp * 16 + n] : br0g[cp * 16 + n];

  if (tid < 64) sWa1[tid] = wa1g[tid];
  else if (tid < 256) sWr1[tid - 64] = wr1g[tid - 64];
  for (int i = tid; i < 8 * HSTR; i += 512) sFS[8 * HSTR + i] = (bf16_t)0.f; // zero rows 8..15
  const float ba1v = ba1g[0];
  const float br1v0 = br1g[0], br1v1 = br1g[1], br1v2 = br1g[2];
  __syncthreads();

  for (int tile = blockIdx.x; tile < NTILES; tile += gridDim.x) {
    const int m0 = tile * TROWS;

    // ---- stage X tile: gathered feats (cols 0..63) ----
    {
      int r = tid >> 3, part = tid & 7;
      int m = m0 + r;
      int idx = ind[m];
      const float4* fp = (const float4*)(map_feat + (size_t)idx * 64 + part * 8);
      float4 f0 = fp[0], f1 = fp[1];
      bf16x8 v;
      v[0] = (bf16_t)f0.x; v[1] = (bf16_t)f0.y; v[2] = (bf16_t)f0.z; v[3] = (bf16_t)f0.w;
      v[4] = (bf16_t)f1.x; v[5] = (bf16_t)f1.y; v[6] = (bf16_t)f1.z; v[7] = (bf16_t)f1.w;
      *(bf16x8*)(sX + r * XSTR + part * 8) = v;
    }
    // ---- posenc cols 64..95 (+w) : one thread per row ----
    if (tid < 64) {
      int m = m0 + tid;
      int idx = ind[m];
      int g = m >> 3;
      float ox = sample_xyz[g * 3 + 0] - map_xyz[idx * 3 + 0];
      float oy = sample_xyz[g * 3 + 1] - map_xyz[idx * 3 + 1];
      float oz = sample_xyz[g * 3 + 2] - map_xyz[idx * 3 + 2];
      sWt[tid] = __expf(-10.f * sqrtf(ox * ox + oy * oy + oz * oz));
      float o3[3] = {ox, oy, oz};
      bf16_t* xr = sX + tid * XSTR + 64;
#pragma unroll
      for (int d = 0; d < 3; d++) {
        float x = o3[d];
        bf16x8 e;
        float fr = 1.f;
#pragma unroll
        for (int i = 0; i < 4; i++) {
          e[i]     = (bf16_t)__sinf(x * fr);
          e[4 + i] = (bf16_t)__cosf(x * fr);
          fr *= 2.f;
        }
        *(bf16x8*)(xr + d * 8) = e;
      }
      bf16x8 z = {};
      *(bf16x8*)(xr + 24) = z;   // pad cols 88..95
    }
    __syncthreads();   // B1: X, w ready

    if (tid < 8) {
      float ss = 0.f;
#pragma unroll
      for (int k = 0; k < 8; k++) ss += sWt[tid * 8 + k];
      sWs[tid] = ss;
    }

    // ---- layer 0: sX -> sHa ----
    {
      f32x4 acc[2][2] = {};
#pragma unroll
      for (int g = 0; g < 2; g++) {
        const bf16_t* xb = sX + ((rh * 2 + g) * 16 + n) * XSTR + q * 8;
#pragma unroll
        for (int s = 0; s < 3; s++) {
          bf16x8 a = *(const bf16x8*)(xb + s * 32);
          acc[g][0] = __builtin_amdgcn_mfma_f32_16x16x32_bf16(a, w0f[0][s], acc[g][0], 0, 0, 0);
          acc[g][1] = __builtin_amdgcn_mfma_f32_16x16x32_bf16(a, w0f[1][s], acc[g][1], 0, 0, 0);
        }
      }
#pragma unroll
      for (int g = 0; g < 2; g++)
#pragma unroll
        for (int nt = 0; nt < 2; nt++)
#pragma unroll
          for (int i = 0; i < 4; i++) {
            float v = acc[g][nt][i] + bias0[nt];
            v = (v >= 0.f) ? v : 0.1f * v;
            sHa[((rh * 2 + g) * 16 + q * 4 + i) * HSTR + (cp * 2 + nt) * 16 + n] = (bf16_t)v;
          }
    }
    __syncthreads();   // B2

    // ---- layers 1 & 2 ----
    auto mlp_layer = [&](const bf16_t* Hin, bf16_t* Hout, bf16x8 (&wf)[2][4], float* bias) {
      f32x4 acc[2][2] = {};
#pragma unroll
      for (int g = 0; g < 2; g++) {
        const bf16_t* hb = Hin + ((rh * 2 + g) * 16 + n) * HSTR + q * 8;
#pragma unroll
        for (int s = 0; s < 4; s++) {
          bf16x8 a = *(const bf16x8*)(hb + s * 32);
          acc[g][0] = __builtin_amdgcn_mfma_f32_16x16x32_bf16(a, wf[0][s], acc[g][0], 0, 0, 0);
          acc[g][1] = __builtin_amdgcn_mfma_f32_16x16x32_bf16(a, wf[1][s], acc[g][1], 0, 0, 0);
        }
      }
#pragma unroll
      for (int g = 0; g < 2; g++)
#pragma unroll
        for (int nt = 0; nt < 2; nt++)
#pragma unroll
          for (int i = 0; i < 4; i++) {
            float v = acc[g][nt][i] + bias[nt];
            v = (v >= 0.f) ? v : 0.1f * v;
            Hout[((rh * 2 + g) * 16 + q * 4 + i) * HSTR + (cp * 2 + nt) * 16 + n] = (bf16_t)v;
          }
    };
    mlp_layer(sHa, sHb, w1f, bias1);
    __syncthreads();   // B3
    mlp_layer(sHb, sHa, w2f, bias2);
    __syncthreads();   // B4: H3 in sHa

    // ---- K-reduce: feat_s (fp32 math, bf16 store) ----
    {
      int j = tid >> 6;
      int c = (tid & 63) * 2;
      float a0 = 0.f, a1 = 0.f;
#pragma unroll
      for (int k = 0; k < 8; k++) {
        float wk = sWt[j * 8 + k];
        unsigned u = *(const unsigned*)(sHa + (j * 8 + k) * HSTR + c);
        a0 += wk * __uint_as_float(u << 16);
        a1 += wk * __uint_as_float(u & 0xffff0000u);
      }
      float inv = 1.f / sWs[j];
      sFS[j * HSTR + c]     = (bf16_t)(a0 * inv);
      sFS[j * HSTR + c + 1] = (bf16_t)(a1 * inv);
    }
    __syncthreads();   // B5: feat_s ready

    // ---- heads: waves 0..3 -> A-head cols, 4..7 -> R-head cols ----
    {
      f32x4 ha = {};
      const bf16_t* fb = sFS + n * HSTR + q * 8;
#pragma unroll
      for (int s = 0; s < 4; s++) {
        bf16x8 a = *(const bf16x8*)(fb + s * 32);
        ha = __builtin_amdgcn_mfma_f32_16x16x32_bf16(a, hdf[s], ha, 0, 0, 0);
      }
      if (q < 2) {   // valid sample rows 0..7
        float* dst = (wid < 4) ? sA : sR;
#pragma unroll
        for (int i = 0; i < 4; i++) {
          float v = ha[i] + biasH;
          v = (v >= 0.f) ? v : 0.1f * v;
          dst[(q * 4 + i) * 68 + cp * 16 + n] = v;
        }
      }
    }
    __syncthreads();   // B6

    // ---- finals: alpha (8 thr) + rgb (24 thr) ----
    if (tid < 8) {
      float x = ba1v;
#pragma unroll
      for (int h = 0; h < 64; h++) x += sA[tid * 68 + h] * sWa1[h];
      float alpha = 1.f / (1.f + __expf(-x));
      ar_out[(size_t)(m0 / 8 + tid) * 4 + 3] = alpha;
    } else if (tid < 32) {
      int j = (tid - 8) / 3, ch = (tid - 8) % 3;
      float x = (ch == 0) ? br1v0 : (ch == 1) ? br1v1 : br1v2;
#pragma unroll
      for (int h = 0; h < 64; h++) x += sR[j * 68 + h] * sWr1[h * 3 + ch];
      float col = 1.f / (1.f + __expf(-x));
      ar_out[(size_t)(m0 / 8 + j) * 4 + ch] = col;
    }
    // no trailing barrier needed: next writes (sX/sWt) are only read before B5,
    // and all threads have passed B6 before any thread re-stages.
  }
}

// ---------------------------------------------------------------------------
// Volume rendering: 1 thread per ray, exact fp32 sequential cumprod.
// ---------------------------------------------------------------------------
__global__ void render_kernel(const float* __restrict__ ar, const float* __restrict__ dcam,
                              float* __restrict__ out) {
  int p = blockIdx.x * blockDim.x + threadIdx.x;
  if (p >= NPIX) return;
  const float4* arv = (const float4*)ar;
  float T = 1.f, cr = 0.f, cg = 0.f, cb = 0.f, cd = 0.f, ca = 0.f;
#pragma unroll 8
  for (int s = 0; s < NS; s++) {
    float4 v = arv[p * NS + s];
    float alpha = v.w;
    float bl = alpha * T;
    cr += v.x * bl; cg += v.y * bl; cb += v.z * bl;
    float dist = 1.f + 1.25f * dcam[p * NS + s];   // DEPTH_MIN + DEPTH_MAX*d/STEPS
    cd += dist * bl;
    ca += bl;
    T *= (1.f - alpha + 1e-10f);
  }
  out[p * 5 + 0] = cr; out[p * 5 + 1] = cg; out[p * 5 + 2] = cb;
  out[p * 5 + 3] = cd; out[p * 5 + 4] = ca;
}

// ---------------------------------------------------------------------------
extern "C" void kernel_launch(void* const* d_in, const int* in_sizes, int n_in,
                              void* d_out, int out_size, void* d_ws, size_t ws_size,
                              hipStream_t stream) {
  const float* map_xyz    = (const float*)d_in[0];
  const float* map_feat   = (const float*)d_in[1];
  const int*   ind        = (const int*)d_in[2];
  const float* sample_xyz = (const float*)d_in[3];
  const float* dist_cam   = (const float*)d_in[4];
  const float* W0  = (const float*)d_in[5];
  const float* b0  = (const float*)d_in[6];
  const float* W1  = (const float*)d_in[7];
  const float* b1  = (const float*)d_in[8];
  const float* W2  = (const float*)d_in[9];
  const float* b2  = (const float*)d_in[10];
  const float* Wa0 = (const float*)d_in[11];
  const float* ba0 = (const float*)d_in[12];
  const float* Wa1 = (const float*)d_in[13];
  const float* ba1 = (const float*)d_in[14];
  const float* Wr0 = (const float*)d_in[15];
  const float* br0 = (const float*)d_in[16];
  const float* Wr1 = (const float*)d_in[17];
  const float* br1 = (const float*)d_in[18];

  bf16_t* wpack = (bf16_t*)d_ws;
  float*  ar    = (float*)((char*)d_ws + WS_AR_BYTES);

  pack_weights<<<240, 256, 0, stream>>>(W0, W1, W2, Wa0, Wr0, wpack);
  nerf_main<<<256, 512, 0, stream>>>(map_xyz, map_feat, ind, sample_xyz,
                                     b0, b1, b2, ba0, Wa1, ba1, br0, Wr1, br1,
                                     wpack, ar);
  render_kernel<<<8, 256, 0, stream>>>(ar, dist_cam, (float*)d_out);
}

// Round 4
// 418.487 us; speedup vs baseline: 1.1803x; 1.1803x over previous
//
#include <hip/hip_runtime.h>

typedef __bf16 bf16_t;
typedef __bf16 bf16x8 __attribute__((ext_vector_type(8)));
typedef float  f32x4  __attribute__((ext_vector_type(4)));

#define NPIX 2048
#define NS   64
#define NK   8
#define NSAMP (NPIX*NS)          // 131072
#define NROWS (NSAMP*NK)         // 1048576
#define TROWS 64
#define NTILES (NROWS/TROWS)     // 16384
#define XSTR 104                 // 96 cols + 8 pad (bf16)
#define HSTR 136                 // 128 cols + 8 pad (bf16)

// packed-weight fragment bases (in bf16x8 units)
#define PK_W0 0
#define PK_W1 1536               // W0p: 8 ntiles * 3 ksteps * 64
#define PK_W2 3584               // W1p: 8*4*64 = 2048
#define PK_WA 5632               // W2p: 2048
#define PK_WR 6656               // Wa0p: 4*4*64 = 1024
#define PK_TOT 7680              // Wr0p: 1024 -> total 61440 bf16 = 122880 B

#define WS_AR_BYTES 122880       // float4 per sample after packed weights

// ---------------------------------------------------------------------------
// Pack W (row-major [KD,ND] fp32) into MFMA B-fragment order, bf16:
// elem e = ((t*KS + s)*64 + l)*8 + j  holds  W[s*32 + (l>>4)*8 + j][t*16 + (l&15)]
// ---------------------------------------------------------------------------
__global__ void pack_weights(const float* __restrict__ W0, const float* __restrict__ W1,
                             const float* __restrict__ W2, const float* __restrict__ Wa0,
                             const float* __restrict__ Wr0, bf16_t* __restrict__ dst0) {
  int tid = blockIdx.x * blockDim.x + threadIdx.x;
  if (tid >= PK_TOT * 8) return;
  const float* src; bf16_t* dst; int e, KD, ND, KS;
  if (tid < 12288)      { src = W0;  dst = dst0;         e = tid;         KD = 88;  ND = 128; KS = 3; }
  else if (tid < 28672) { src = W1;  dst = dst0 + 12288; e = tid - 12288; KD = 128; ND = 128; KS = 4; }
  else if (tid < 45056) { src = W2;  dst = dst0 + 28672; e = tid - 28672; KD = 128; ND = 128; KS = 4; }
  else if (tid < 53248) { src = Wa0; dst = dst0 + 45056; e = tid - 45056; KD = 128; ND = 64;  KS = 4; }
  else                  { src = Wr0; dst = dst0 + 53248; e = tid - 53248; KD = 128; ND = 64;  KS = 4; }
  int j = e & 7, l = (e >> 3) & 63, f = e >> 9;
  int s = f % KS, t = f / KS;
  int row = s * 32 + (l >> 4) * 8 + j;
  int col = t * 16 + (l & 15);
  float v = (row < KD) ? src[row * ND + col] : 0.f;
  dst[e] = (bf16_t)v;
}

// ---------------------------------------------------------------------------
// Main fused kernel. Block: 512 thr (8 waves). Wave w owns OUTPUT COLUMNS
// 16w..16w+15 for all 64 tile rows (8-way column split, no row split):
// weight fragments are not duplicated across waves -> 15 frags (60 VGPRs).
// sX aliases the layer-1 output buffer (sBuf) to cut LDS to ~45 KB so two
// blocks fit per CU alongside the __launch_bounds__(512,4) register cap.
// (This body is round-2's: proven correct by identical-ar evidence in r2/r3.)
// ---------------------------------------------------------------------------
__global__ __launch_bounds__(512, 4)
void nerf_main(const float* __restrict__ map_xyz, const float* __restrict__ map_feat,
               const int* __restrict__ ind, const float* __restrict__ sample_xyz,
               const float* __restrict__ b0g, const float* __restrict__ b1g,
               const float* __restrict__ b2g, const float* __restrict__ ba0g,
               const float* __restrict__ wa1g, const float* __restrict__ ba1g,
               const float* __restrict__ br0g, const float* __restrict__ wr1g,
               const float* __restrict__ br1g, const bf16_t* __restrict__ wpack,
               float* __restrict__ ar_out)
{
  __shared__ __align__(16) bf16_t sBuf[TROWS * HSTR];   // X tile (XSTR view) / H1
  __shared__ __align__(16) bf16_t sHa[TROWS * HSTR];    // H0 / H2
  __shared__ __align__(16) bf16_t sFS[16 * HSTR];       // feat_s (rows 8..15 zero)
  __shared__ float sWt[TROWS];
  __shared__ float sWs[8];
  __shared__ float sA[8 * 68];
  __shared__ float sR[8 * 68];
  __shared__ float sWa1[64];
  __shared__ float sWr1[192];

  const int tid = threadIdx.x;
  const int wid = tid >> 6, l = tid & 63;
  const int q = l >> 4, n = l & 15;

  // ---- persistent register B-fragments: wave w owns cols 16w..16w+15 ----
  const bf16x8* pk = (const bf16x8*)wpack;
  bf16x8 w0f[3], w1f[4], w2f[4], hdf[4];
#pragma unroll
  for (int s = 0; s < 3; s++) w0f[s] = pk[PK_W0 + (wid * 3 + s) * 64 + l];
#pragma unroll
  for (int s = 0; s < 4; s++) w1f[s] = pk[PK_W1 + (wid * 4 + s) * 64 + l];
#pragma unroll
  for (int s = 0; s < 4; s++) w2f[s] = pk[PK_W2 + (wid * 4 + s) * 64 + l];
#pragma unroll
  for (int s = 0; s < 4; s++)
    hdf[s] = pk[(wid < 4 ? PK_WA : PK_WR) + ((wid & 3) * 4 + s) * 64 + l];

  const int col = wid * 16 + n;
  const float bias0 = b0g[col], bias1 = b1g[col], bias2 = b2g[col];
  const float biasH = (wid < 4) ? ba0g[(wid & 3) * 16 + n] : br0g[(wid & 3) * 16 + n];

  if (tid < 64) sWa1[tid] = wa1g[tid];
  else if (tid < 256) sWr1[tid - 64] = wr1g[tid - 64];
  for (int i = tid; i < 8 * HSTR; i += 512) sFS[8 * HSTR + i] = (bf16_t)0.f; // rows 8..15
  const float ba1v = ba1g[0];
  const float br1v0 = br1g[0], br1v1 = br1g[1], br1v2 = br1g[2];
  __syncthreads();

  for (int tile = blockIdx.x; tile < NTILES; tile += gridDim.x) {
    const int m0 = tile * TROWS;

    // ---- stage X tile into sBuf (XSTR view): gathered feats cols 0..63 ----
    {
      int r = tid >> 3, part = tid & 7;
      int idx = ind[m0 + r];
      const float4* fp = (const float4*)(map_feat + (size_t)idx * 64 + part * 8);
      float4 f0 = fp[0], f1 = fp[1];
      bf16x8 v;
      v[0] = (bf16_t)f0.x; v[1] = (bf16_t)f0.y; v[2] = (bf16_t)f0.z; v[3] = (bf16_t)f0.w;
      v[4] = (bf16_t)f1.x; v[5] = (bf16_t)f1.y; v[6] = (bf16_t)f1.z; v[7] = (bf16_t)f1.w;
      *(bf16x8*)(sBuf + r * XSTR + part * 8) = v;
    }
    // ---- posenc cols 64..95 (+w): one thread per row ----
    if (tid < 64) {
      int m = m0 + tid;
      int idx = ind[m];
      int g = m >> 3;
      float ox = sample_xyz[g * 3 + 0] - map_xyz[idx * 3 + 0];
      float oy = sample_xyz[g * 3 + 1] - map_xyz[idx * 3 + 1];
      float oz = sample_xyz[g * 3 + 2] - map_xyz[idx * 3 + 2];
      sWt[tid] = __expf(-10.f * sqrtf(ox * ox + oy * oy + oz * oz));
      float o3[3] = {ox, oy, oz};
      bf16_t* xr = sBuf + tid * XSTR + 64;
#pragma unroll
      for (int d = 0; d < 3; d++) {
        float x = o3[d];
        bf16x8 e;
        float fr = 1.f;
#pragma unroll
        for (int i = 0; i < 4; i++) {
          e[i]     = (bf16_t)__sinf(x * fr);
          e[4 + i] = (bf16_t)__cosf(x * fr);
          fr *= 2.f;
        }
        *(bf16x8*)(xr + d * 8) = e;
      }
      bf16x8 z = {};
      *(bf16x8*)(xr + 24) = z;   // pad cols 88..95
    }
    __syncthreads();   // B1: X, w ready

    if (tid < 8) {
      float ss = 0.f;
#pragma unroll
      for (int k = 0; k < 8; k++) ss += sWt[tid * 8 + k];
      sWs[tid] = ss;
    }

    // ---- layer 0: sBuf(X) -> sHa ----
    {
      f32x4 acc[4] = {};
#pragma unroll
      for (int s = 0; s < 3; s++)
#pragma unroll
        for (int g = 0; g < 4; g++) {
          bf16x8 a = *(const bf16x8*)(sBuf + (g * 16 + n) * XSTR + s * 32 + q * 8);
          acc[g] = __builtin_amdgcn_mfma_f32_16x16x32_bf16(a, w0f[s], acc[g], 0, 0, 0);
        }
#pragma unroll
      for (int g = 0; g < 4; g++)
#pragma unroll
        for (int i = 0; i < 4; i++) {
          float v = acc[g][i] + bias0;
          v = (v >= 0.f) ? v : 0.1f * v;
          sHa[(g * 16 + q * 4 + i) * HSTR + col] = (bf16_t)v;
        }
    }
    __syncthreads();   // B2

    // ---- layers 1 & 2 ----
    auto mlp_layer = [&](const bf16_t* In, bf16_t* Out, bf16x8 (&wf)[4], float bias) {
      f32x4 acc[4] = {};
#pragma unroll
      for (int s = 0; s < 4; s++)
#pragma unroll
        for (int g = 0; g < 4; g++) {
          bf16x8 a = *(const bf16x8*)(In + (g * 16 + n) * HSTR + s * 32 + q * 8);
          acc[g] = __builtin_amdgcn_mfma_f32_16x16x32_bf16(a, wf[s], acc[g], 0, 0, 0);
        }
#pragma unroll
      for (int g = 0; g < 4; g++)
#pragma unroll
        for (int i = 0; i < 4; i++) {
          float v = acc[g][i] + bias;
          v = (v >= 0.f) ? v : 0.1f * v;
          Out[(g * 16 + q * 4 + i) * HSTR + col] = (bf16_t)v;
        }
    };
    mlp_layer(sHa, sBuf, w1f, bias1);
    __syncthreads();   // B3
    mlp_layer(sBuf, sHa, w2f, bias2);
    __syncthreads();   // B4: H3 in sHa

    // ---- K-reduce: feat_s (fp32 math, bf16 store) ----
    {
      int j = tid >> 6;
      int c = (tid & 63) * 2;
      float a0 = 0.f, a1 = 0.f;
#pragma unroll
      for (int k = 0; k < 8; k++) {
        float wk = sWt[j * 8 + k];
        unsigned u = *(const unsigned*)(sHa + (j * 8 + k) * HSTR + c);
        a0 += wk * __uint_as_float(u << 16);
        a1 += wk * __uint_as_float(u & 0xffff0000u);
      }
      float inv = 1.f / sWs[j];
      sFS[j * HSTR + c]     = (bf16_t)(a0 * inv);
      sFS[j * HSTR + c + 1] = (bf16_t)(a1 * inv);
    }
    __syncthreads();   // B5: feat_s ready

    // ---- heads: waves 0..3 -> A-head cols, 4..7 -> R-head cols ----
    {
      f32x4 ha = {};
#pragma unroll
      for (int s = 0; s < 4; s++) {
        bf16x8 a = *(const bf16x8*)(sFS + n * HSTR + s * 32 + q * 8);
        ha = __builtin_amdgcn_mfma_f32_16x16x32_bf16(a, hdf[s], ha, 0, 0, 0);
      }
      if (q < 2) {   // valid sample rows 0..7
        float* dst = (wid < 4) ? sA : sR;
#pragma unroll
        for (int i = 0; i < 4; i++) {
          float v = ha[i] + biasH;
          v = (v >= 0.f) ? v : 0.1f * v;
          dst[(q * 4 + i) * 68 + (wid & 3) * 16 + n] = v;
        }
      }
    }
    __syncthreads();   // B6

    // ---- finals: alpha (8 thr) + rgb (24 thr) ----
    if (tid < 8) {
      float x = ba1v;
#pragma unroll
      for (int h = 0; h < 64; h++) x += sA[tid * 68 + h] * sWa1[h];
      float alpha = 1.f / (1.f + __expf(-x));
      ar_out[(size_t)(m0 / 8 + tid) * 4 + 3] = alpha;
    } else if (tid < 32) {
      int j = (tid - 8) / 3, ch = (tid - 8) % 3;
      float x = (ch == 0) ? br1v0 : (ch == 1) ? br1v1 : br1v2;
#pragma unroll
      for (int h = 0; h < 64; h++) x += sR[j * 68 + h] * sWr1[h * 3 + ch];
      float c2 = 1.f / (1.f + __expf(-x));
      ar_out[(size_t)(m0 / 8 + j) * 4 + ch] = c2;
    }
    // no trailing barrier needed: staging writes (sBuf/sWt) happen only after
    // each writer passed B6; sA/sR are re-written only between the next tile's
    // B5 and B6, and every thread (incl. finals readers) must reach next-B5
    // first, which happens only after finals complete.
  }
}

// ---------------------------------------------------------------------------
// Volume rendering: one wave per ray; lane s holds sample s. Transmittance
// via shuffle-based inclusive product scan, sums via butterfly reduction.
// NOTE: all cross-lane ops execute with FULL exec mask. ds_bpermute (the
// __shfl_* lowering) returns undefined/0 when the SOURCE lane is inactive,
// so a shuffle inside divergent control flow (e.g. the else-arm of a ternary)
// silently corrupts lane 1 — that was the round-2/3 absmax=22 bug.
// ---------------------------------------------------------------------------
__global__ __launch_bounds__(512)
void render_kernel(const float* __restrict__ ar, const float* __restrict__ dcam,
                   float* __restrict__ out) {
  int ray = blockIdx.x * 8 + (threadIdx.x >> 6);
  int s = threadIdx.x & 63;
  float4 v = ((const float4*)ar)[ray * 64 + s];
  float alpha = v.w;
  float t = 1.f - alpha + 1e-10f;
  // inclusive scan (product) over the wave — shuffles unconditional
  float p = t;
#pragma unroll
  for (int d = 1; d < 64; d <<= 1) {
    float o = __shfl_up(p, d);
    if (s >= d) p *= o;
  }
  float pm1 = __shfl_up(p, 1);                // unconditional: all lanes active
  float T = (s == 0) ? 1.f : pm1;             // exclusive product
  float bl = alpha * T;
  float dist = 1.f + 1.25f * dcam[ray * 64 + s];  // DEPTH_MIN + DEPTH_MAX*d/STEPS
  float cr = v.x * bl, cg = v.y * bl, cb = v.z * bl, cd = dist * bl, ca = bl;
#pragma unroll
  for (int d = 32; d > 0; d >>= 1) {
    cr += __shfl_xor(cr, d);
    cg += __shfl_xor(cg, d);
    cb += __shfl_xor(cb, d);
    cd += __shfl_xor(cd, d);
    ca += __shfl_xor(ca, d);
  }
  if (s == 0) {
    out[ray * 5 + 0] = cr; out[ray * 5 + 1] = cg; out[ray * 5 + 2] = cb;
    out[ray * 5 + 3] = cd; out[ray * 5 + 4] = ca;
  }
}

// ---------------------------------------------------------------------------
extern "C" void kernel_launch(void* const* d_in, const int* in_sizes, int n_in,
                              void* d_out, int out_size, void* d_ws, size_t ws_size,
                              hipStream_t stream) {
  const float* map_xyz    = (const float*)d_in[0];
  const float* map_feat   = (const float*)d_in[1];
  const int*   ind        = (const int*)d_in[2];
  const float* sample_xyz = (const float*)d_in[3];
  const float* dist_cam   = (const float*)d_in[4];
  const float* W0  = (const float*)d_in[5];
  const float* b0  = (const float*)d_in[6];
  const float* W1  = (const float*)d_in[7];
  const float* b1  = (const float*)d_in[8];
  const float* W2  = (const float*)d_in[9];
  const float* b2  = (const float*)d_in[10];
  const float* Wa0 = (const float*)d_in[11];
  const float* ba0 = (const float*)d_in[12];
  const float* Wa1 = (const float*)d_in[13];
  const float* ba1 = (const float*)d_in[14];
  const float* Wr0 = (const float*)d_in[15];
  const float* br0 = (const float*)d_in[16];
  const float* Wr1 = (const float*)d_in[17];
  const float* br1 = (const float*)d_in[18];

  bf16_t* wpack = (bf16_t*)d_ws;
  float*  ar    = (float*)((char*)d_ws + WS_AR_BYTES);

  pack_weights<<<240, 256, 0, stream>>>(W0, W1, W2, Wa0, Wr0, wpack);
  nerf_main<<<512, 512, 0, stream>>>(map_xyz, map_feat, ind, sample_xyz,
                                     b0, b1, b2, ba0, Wa1, ba1, br0, Wr1, br1,
                                     wpack, ar);
  render_kernel<<<256, 512, 0, stream>>>(ar, dist_cam, (float*)d_out);
}

// Round 5
// 417.145 us; speedup vs baseline: 1.1841x; 1.0032x over previous
//
#include <hip/hip_runtime.h>

typedef __bf16 bf16_t;
typedef __bf16 bf16x4 __attribute__((ext_vector_type(4)));
typedef __bf16 bf16x8 __attribute__((ext_vector_type(8)));
typedef float  f32x4  __attribute__((ext_vector_type(4)));

#define NPIX 2048
#define NS   64
#define NK   8
#define NSAMP (NPIX*NS)          // 131072
#define NROWS (NSAMP*NK)         // 1048576
#define TROWS 64
#define NTILES (NROWS/TROWS)     // 16384
#define XSTR 104                 // 96 cols + 8 pad (bf16)
#define HSTR 136                 // 128 cols + 8 pad (bf16)

// packed-weight fragment bases (in bf16x8 units)
#define PK_W0 0
#define PK_W1 1536               // W0p: 8 ntiles * 3 ksteps * 64
#define PK_W2 3584               // W1p: 8*4*64 = 2048
#define PK_WA 5632               // W2p: 2048
#define PK_WR 6656               // Wa0p: 4*4*64 = 1024
#define PK_TOT 7680              // Wr0p: 1024 -> total 61440 bf16 = 122880 B

#define WS_AR_BYTES 122880       // float4 per sample after packed weights

// ---------------------------------------------------------------------------
// Pack W (row-major [KD,ND] fp32) into MFMA B-fragment order, bf16:
// elem e = ((t*KS + s)*64 + l)*8 + j  holds  W[s*32 + (l>>4)*8 + j][t*16 + (l&15)]
// ---------------------------------------------------------------------------
__global__ void pack_weights(const float* __restrict__ W0, const float* __restrict__ W1,
                             const float* __restrict__ W2, const float* __restrict__ Wa0,
                             const float* __restrict__ Wr0, bf16_t* __restrict__ dst0) {
  int tid = blockIdx.x * blockDim.x + threadIdx.x;
  if (tid >= PK_TOT * 8) return;
  const float* src; bf16_t* dst; int e, KD, ND, KS;
  if (tid < 12288)      { src = W0;  dst = dst0;         e = tid;         KD = 88;  ND = 128; KS = 3; }
  else if (tid < 28672) { src = W1;  dst = dst0 + 12288; e = tid - 12288; KD = 128; ND = 128; KS = 4; }
  else if (tid < 45056) { src = W2;  dst = dst0 + 28672; e = tid - 28672; KD = 128; ND = 128; KS = 4; }
  else if (tid < 53248) { src = Wa0; dst = dst0 + 45056; e = tid - 45056; KD = 128; ND = 64;  KS = 4; }
  else                  { src = Wr0; dst = dst0 + 53248; e = tid - 53248; KD = 128; ND = 64;  KS = 4; }
  int j = e & 7, l = (e >> 3) & 63, f = e >> 9;
  int s = f % KS, t = f / KS;
  int row = s * 32 + (l >> 4) * 8 + j;
  int col = t * 16 + (l & 15);
  float v = (row < KD) ? src[row * ND + col] : 0.f;
  dst[e] = (bf16_t)v;
}

__device__ __forceinline__ float lrelu(float v) { return fmaxf(v, 0.1f * v); }
__device__ __forceinline__ float sigmoidf(float x) { return 1.f / (1.f + __expf(-x)); }

// ---------------------------------------------------------------------------
// Main fused kernel. Block: 512 thr (8 waves). Wave w owns OUTPUT COLUMNS
// 16w..16w+15 for all 64 tile rows; 15 weight B-fragments live in registers.
// Round-5 changes vs round-4 (theory: kill wave-0 serial chains + LDS trip):
//  * posenc spread over all 512 threads (double-angle chain, 2 trans/thread)
//  * K-reduce fused into layer-2 epilogue via __shfl_xor(.,16) partial-pair
//    (H3 never touches LDS; barrier count 6 -> 5)
//  * finals: wave w reduces sample w's 4 dots via butterfly shuffles
// ---------------------------------------------------------------------------
__global__ __launch_bounds__(512, 4)
void nerf_main(const float* __restrict__ map_xyz, const float* __restrict__ map_feat,
               const int* __restrict__ ind, const float* __restrict__ sample_xyz,
               const float* __restrict__ b0g, const float* __restrict__ b1g,
               const float* __restrict__ b2g, const float* __restrict__ ba0g,
               const float* __restrict__ wa1g, const float* __restrict__ ba1g,
               const float* __restrict__ br0g, const float* __restrict__ wr1g,
               const float* __restrict__ br1g, const bf16_t* __restrict__ wpack,
               float* __restrict__ ar_out)
{
  __shared__ __align__(16) bf16_t sBuf[TROWS * HSTR];   // X tile (XSTR view) / H1
  __shared__ __align__(16) bf16_t sHa[TROWS * HSTR];    // H0
  __shared__ __align__(16) bf16_t sFS[16 * HSTR];       // feat_s (rows 8..15 zero)
  __shared__ __align__(16) float sWt[TROWS];
  __shared__ float sWs[8];
  __shared__ float sA[8 * 68];
  __shared__ float sR[8 * 68];
  __shared__ float sWa1[64];
  __shared__ float sWr1[192];

  const int tid = threadIdx.x;
  const int wid = tid >> 6, l = tid & 63;
  const int q = l >> 4, n = l & 15;

  // ---- persistent register B-fragments: wave w owns cols 16w..16w+15 ----
  const bf16x8* pk = (const bf16x8*)wpack;
  bf16x8 w0f[3], w1f[4], w2f[4], hdf[4];
#pragma unroll
  for (int s = 0; s < 3; s++) w0f[s] = pk[PK_W0 + (wid * 3 + s) * 64 + l];
#pragma unroll
  for (int s = 0; s < 4; s++) w1f[s] = pk[PK_W1 + (wid * 4 + s) * 64 + l];
#pragma unroll
  for (int s = 0; s < 4; s++) w2f[s] = pk[PK_W2 + (wid * 4 + s) * 64 + l];
#pragma unroll
  for (int s = 0; s < 4; s++)
    hdf[s] = pk[(wid < 4 ? PK_WA : PK_WR) + ((wid & 3) * 4 + s) * 64 + l];

  const int col = wid * 16 + n;
  const float bias0 = b0g[col], bias1 = b1g[col], bias2 = b2g[col];
  const float biasH = (wid < 4) ? ba0g[(wid & 3) * 16 + n] : br0g[(wid & 3) * 16 + n];

  if (tid < 64) sWa1[tid] = wa1g[tid];
  else if (tid < 256) sWr1[tid - 64] = wr1g[tid - 64];
  for (int i = tid; i < 8 * HSTR; i += 512) sFS[8 * HSTR + i] = (bf16_t)0.f; // rows 8..15
  const float ba1v = ba1g[0];
  const float br1v0 = br1g[0], br1v1 = br1g[1], br1v2 = br1g[2];
  __syncthreads();

  for (int tile = blockIdx.x; tile < NTILES; tile += gridDim.x) {
    const int m0 = tile * TROWS;

    // ---- staging: thread (r = tid>>3, p = tid&7) ----
    {
      const int r = tid >> 3, p = tid & 7;
      const int m = m0 + r;
      const int idx = ind[m];
      // gathered feats: cols p*8 .. p*8+7
      const float4* fp = (const float4*)(map_feat + (size_t)idx * 64 + p * 8);
      float4 f0 = fp[0], f1 = fp[1];
      bf16x8 v;
      v[0] = (bf16_t)f0.x; v[1] = (bf16_t)f0.y; v[2] = (bf16_t)f0.z; v[3] = (bf16_t)f0.w;
      v[4] = (bf16_t)f1.x; v[5] = (bf16_t)f1.y; v[6] = (bf16_t)f1.z; v[7] = (bf16_t)f1.w;
      *(bf16x8*)(sBuf + r * XSTR + p * 8) = v;
      // posenc spread across parts: p<6 -> 4 sin or cos values of dim p>>1
      const int g = m >> 3;
      if (p < 6) {
        const int d = p >> 1;
        float o = sample_xyz[g * 3 + d] - map_xyz[idx * 3 + d];
        float s1 = __sinf(o), c1 = __cosf(o);
        float s2 = 2.f * s1 * c1, c2 = 1.f - 2.f * s1 * s1;
        float s4 = 2.f * s2 * c2, c4 = 1.f - 2.f * s2 * s2;
        float s8 = 2.f * s4 * c4, c8 = 1.f - 2.f * s4 * s4;
        bf16x4 e;
        if (p & 1) { e[0] = (bf16_t)c1; e[1] = (bf16_t)c2; e[2] = (bf16_t)c4; e[3] = (bf16_t)c8; }
        else       { e[0] = (bf16_t)s1; e[1] = (bf16_t)s2; e[2] = (bf16_t)s4; e[3] = (bf16_t)s8; }
        *(bf16x4*)(sBuf + r * XSTR + 64 + d * 8 + (p & 1) * 4) = e;
      } else if (p == 6) {
        bf16x8 z = {};
        *(bf16x8*)(sBuf + r * XSTR + 88) = z;   // pad cols 88..95
      } else {
        float ox = sample_xyz[g * 3 + 0] - map_xyz[idx * 3 + 0];
        float oy = sample_xyz[g * 3 + 1] - map_xyz[idx * 3 + 1];
        float oz = sample_xyz[g * 3 + 2] - map_xyz[idx * 3 + 2];
        sWt[r] = __expf(-10.f * sqrtf(ox * ox + oy * oy + oz * oz));
      }
    }
    __syncthreads();   // B1: X, wt ready

    if (tid < 8) {
      float ss = 0.f;
#pragma unroll
      for (int k = 0; k < 8; k++) ss += sWt[tid * 8 + k];
      sWs[tid] = ss;
    }

    // ---- layer 0: sBuf(X) -> sHa ----
    {
      f32x4 acc[4] = {};
#pragma unroll
      for (int s = 0; s < 3; s++)
#pragma unroll
        for (int g = 0; g < 4; g++) {
          bf16x8 a = *(const bf16x8*)(sBuf + (g * 16 + n) * XSTR + s * 32 + q * 8);
          acc[g] = __builtin_amdgcn_mfma_f32_16x16x32_bf16(a, w0f[s], acc[g], 0, 0, 0);
        }
#pragma unroll
      for (int g = 0; g < 4; g++)
#pragma unroll
        for (int i = 0; i < 4; i++) {
          float v = lrelu(acc[g][i] + bias0);
          sHa[(g * 16 + q * 4 + i) * HSTR + col] = (bf16_t)v;
        }
    }
    __syncthreads();   // B2

    // ---- layer 1: sHa -> sBuf ----
    {
      f32x4 acc[4] = {};
#pragma unroll
      for (int s = 0; s < 4; s++)
#pragma unroll
        for (int g = 0; g < 4; g++) {
          bf16x8 a = *(const bf16x8*)(sHa + (g * 16 + n) * HSTR + s * 32 + q * 8);
          acc[g] = __builtin_amdgcn_mfma_f32_16x16x32_bf16(a, w1f[s], acc[g], 0, 0, 0);
        }
#pragma unroll
      for (int g = 0; g < 4; g++)
#pragma unroll
        for (int i = 0; i < 4; i++) {
          float v = lrelu(acc[g][i] + bias1);
          sBuf[(g * 16 + q * 4 + i) * HSTR + col] = (bf16_t)v;
        }
    }
    __syncthreads();   // B3

    // ---- layer 2 + fused K-reduce: sBuf -> regs -> sFS ----
    // Lane (q,n), group g holds H3 rows g*16+q*4+i (i=0..3), col = wid*16+n.
    // Sample j = 2g + (q>>1); lane's 4 rows are k = 4*(q&1)+i of that sample.
    // Partner lane^16 holds the complementary 4 k's.
    {
      f32x4 acc[4] = {};
#pragma unroll
      for (int s = 0; s < 4; s++)
#pragma unroll
        for (int g = 0; g < 4; g++) {
          bf16x8 a = *(const bf16x8*)(sBuf + (g * 16 + n) * HSTR + s * 32 + q * 8);
          acc[g] = __builtin_amdgcn_mfma_f32_16x16x32_bf16(a, w2f[s], acc[g], 0, 0, 0);
        }
#pragma unroll
      for (int g = 0; g < 4; g++) {
        const int j = 2 * g + (q >> 1);
        const float4 wt4 = *(const float4*)(sWt + j * 8 + 4 * (q & 1));
        float part = 0.f;
#pragma unroll
        for (int i = 0; i < 4; i++) {
          float v = lrelu(acc[g][i] + bias2);
          part += ((const float*)&wt4)[i] * v;
        }
        part += __shfl_xor(part, 16);        // unconditional: full exec mask
        float fs = part * __builtin_amdgcn_rcpf(sWs[j]);
        if (!(q & 1)) sFS[j * HSTR + col] = (bf16_t)fs;
      }
    }
    __syncthreads();   // B4: feat_s ready

    // ---- heads: waves 0..3 -> A-head cols, 4..7 -> R-head cols ----
    {
      f32x4 ha = {};
#pragma unroll
      for (int s = 0; s < 4; s++) {
        bf16x8 a = *(const bf16x8*)(sFS + n * HSTR + s * 32 + q * 8);
        ha = __builtin_amdgcn_mfma_f32_16x16x32_bf16(a, hdf[s], ha, 0, 0, 0);
      }
      if (q < 2) {   // valid sample rows 0..7
        float* dst = (wid < 4) ? sA : sR;
#pragma unroll
        for (int i = 0; i < 4; i++) {
          float v = lrelu(ha[i] + biasH);
          dst[(q * 4 + i) * 68 + (wid & 3) * 16 + n] = v;
        }
      }
    }
    __syncthreads();   // B5: sA/sR ready

    // ---- finals: wave w handles sample w; butterfly reductions ----
    {
      float vA = sA[wid * 68 + l];
      float vR = sR[wid * 68 + l];
      float xa = vA * sWa1[l];
      float x0 = vR * sWr1[l * 3 + 0];
      float x1 = vR * sWr1[l * 3 + 1];
      float x2 = vR * sWr1[l * 3 + 2];
#pragma unroll
      for (int d = 32; d > 0; d >>= 1) {
        xa += __shfl_xor(xa, d);
        x0 += __shfl_xor(x0, d);
        x1 += __shfl_xor(x1, d);
        x2 += __shfl_xor(x2, d);
      }
      if (l == 0) {
        float4 o;
        o.x = sigmoidf(x0 + br1v0);
        o.y = sigmoidf(x1 + br1v1);
        o.z = sigmoidf(x2 + br1v2);
        o.w = sigmoidf(xa + ba1v);
        ((float4*)ar_out)[m0 / 8 + wid] = o;
      }
    }
    // no trailing barrier: next staging writes sBuf/sWt, first read again only
    // after next B1/B3; sA/sR rewritten only after next B4, which requires all
    // threads (incl. finals) to have arrived.
  }
}

// ---------------------------------------------------------------------------
// Volume rendering: one wave per ray; lane s holds sample s. Transmittance
// via shuffle-based inclusive product scan, sums via butterfly reduction.
// NOTE: all cross-lane ops execute with FULL exec mask (round-2/3 lesson:
// a shuffle in the else-arm of a ternary reads an inactive lane -> garbage).
// ---------------------------------------------------------------------------
__global__ __launch_bounds__(512)
void render_kernel(const float* __restrict__ ar, const float* __restrict__ dcam,
                   float* __restrict__ out) {
  int ray = blockIdx.x * 8 + (threadIdx.x >> 6);
  int s = threadIdx.x & 63;
  float4 v = ((const float4*)ar)[ray * 64 + s];
  float alpha = v.w;
  float t = 1.f - alpha + 1e-10f;
  float p = t;
#pragma unroll
  for (int d = 1; d < 64; d <<= 1) {
    float o = __shfl_up(p, d);
    if (s >= d) p *= o;
  }
  float pm1 = __shfl_up(p, 1);                // unconditional: all lanes active
  float T = (s == 0) ? 1.f : pm1;             // exclusive product
  float bl = alpha * T;
  float dist = 1.f + 1.25f * dcam[ray * 64 + s];  // DEPTH_MIN + DEPTH_MAX*d/STEPS
  float cr = v.x * bl, cg = v.y * bl, cb = v.z * bl, cd = dist * bl, ca = bl;
#pragma unroll
  for (int d = 32; d > 0; d >>= 1) {
    cr += __shfl_xor(cr, d);
    cg += __shfl_xor(cg, d);
    cb += __shfl_xor(cb, d);
    cd += __shfl_xor(cd, d);
    ca += __shfl_xor(ca, d);
  }
  if (s == 0) {
    out[ray * 5 + 0] = cr; out[ray * 5 + 1] = cg; out[ray * 5 + 2] = cb;
    out[ray * 5 + 3] = cd; out[ray * 5 + 4] = ca;
  }
}

// ---------------------------------------------------------------------------
extern "C" void kernel_launch(void* const* d_in, const int* in_sizes, int n_in,
                              void* d_out, int out_size, void* d_ws, size_t ws_size,
                              hipStream_t stream) {
  const float* map_xyz    = (const float*)d_in[0];
  const float* map_feat   = (const float*)d_in[1];
  const int*   ind        = (const int*)d_in[2];
  const float* sample_xyz = (const float*)d_in[3];
  const float* dist_cam   = (const float*)d_in[4];
  const float* W0  = (const float*)d_in[5];
  const float* b0  = (const float*)d_in[6];
  const float* W1  = (const float*)d_in[7];
  const float* b1  = (const float*)d_in[8];
  const float* W2  = (const float*)d_in[9];
  const float* b2  = (const float*)d_in[10];
  const float* Wa0 = (const float*)d_in[11];
  const float* ba0 = (const float*)d_in[12];
  const float* Wa1 = (const float*)d_in[13];
  const float* ba1 = (const float*)d_in[14];
  const float* Wr0 = (const float*)d_in[15];
  const float* br0 = (const float*)d_in[16];
  const float* Wr1 = (const float*)d_in[17];
  const float* br1 = (const float*)d_in[18];

  bf16_t* wpack = (bf16_t*)d_ws;
  float*  ar    = (float*)((char*)d_ws + WS_AR_BYTES);

  pack_weights<<<240, 256, 0, stream>>>(W0, W1, W2, Wa0, Wr0, wpack);
  nerf_main<<<512, 512, 0, stream>>>(map_xyz, map_feat, ind, sample_xyz,
                                     b0, b1, b2, ba0, Wa1, ba1, br0, Wr1, br1,
                                     wpack, ar);
  render_kernel<<<256, 512, 0, stream>>>(ar, dist_cam, (float*)d_out);
}